// Round 1
// baseline (314.406 us; speedup 1.0000x reference)
//
#include <hip/hip_runtime.h>
#include <math.h>

#define N_NODES 128
#define STRIDE  132      // LDS row stride (floats): 16B-aligned rows, 8-way worst-case banks
#define NTH     512

__device__ __forceinline__ float sp_softplus(float x) {
    return log1pf(expf(x));
}
__device__ __forceinline__ float rdlane(float v, int l) {
    return __int_as_float(__builtin_amdgcn_readlane(__float_as_int(v), l));
}

__global__ void __launch_bounds__(NTH)
ts_gcn_kernel(const float* __restrict__ edge_pred,
              const int*   __restrict__ adj,
              const float* __restrict__ d_init,
              const float* __restrict__ u_init,
              const float* __restrict__ x_noise,
              float* __restrict__ out)
{
    __shared__ float  A0[N_NODES * STRIDE];   // ep ch0 -> D
    __shared__ float  A1[N_NODES * STRIDE];   // ep ch1 -> W
    __shared__ float4 Xs[N_NODES];
    __shared__ float  u_s[N_NODES];
    __shared__ float  r_s[N_NODES];
    __shared__ float4 scr4[NTH];              // reduction scratch (aliased as float)
    __shared__ int    s_cntM, s_cntN0;

    float* scrf = (float*)scr4;

    const int b    = blockIdx.x;
    const int t    = threadIdx.x;
    const int lane = t & 63;
    const int i    = t & 127;      // owned row
    const int q    = t >> 7;       // column quarter
    const int jb   = q * 32;
    const int lsel = jb & 63;      // lane base within u half

    const float dini = d_init[0];

    // ---------------- Phase 1: stage raw edge_pred into LDS (coalesced) ----------------
    const float2* ep2 = (const float2*)edge_pred + (size_t)b * 16384;
    #pragma unroll 4
    for (int e = t; e < 16384; e += NTH) {
        float2 v = ep2[e];
        int ii = e >> 7, jj = e & 127;
        A0[ii*STRIDE + jj] = v.x;
        A1[ii*STRIDE + jj] = v.y;
    }
    if (t == 0) { s_cntM = 0; s_cntN0 = 0; }
    __syncthreads();

    // ---------------- Phase 2: symmetrize + softplus + mask (upper triangle owners) ----
    // owner of pair (ii,jj), ii<jj, reads and writes exactly cells (ii,jj),(jj,ii): no race
    const int* adjb = adj + (size_t)b * 16384;
    int cM = 0, cN0 = 0;
    for (int p = t; p < 8128; p += NTH) {
        float disc = sqrtf((float)(65025 - 8 * p));
        int ii = (int)((255.0f - disc) * 0.5f);
        while ((ii + 1) * (255 - (ii + 1)) / 2 <= p) ++ii;   // exact fixup (<=1 step)
        while (ii * (255 - ii) / 2 > p) --ii;
        int jj = ii + 1 + (p - ii * (255 - ii) / 2);
        int a = adjb[ii * 128 + jj];
        float d = 0.f, w = 0.f;
        if (a) {
            float e0 = A0[ii*STRIDE + jj] + A0[jj*STRIDE + ii];
            float e1 = A1[ii*STRIDE + jj] + A1[jj*STRIDE + ii];
            d = sp_softplus(dini + e0);
            w = sp_softplus(dini + e1);
            cM += 2;                 // both symmetric off-diag mask entries
            if (ii == 0) cN0 += 1;   // column-0 entry (jj,0)
        }
        A0[ii*STRIDE + jj] = d; A0[jj*STRIDE + ii] = d;
        A1[ii*STRIDE + jj] = w; A1[jj*STRIDE + ii] = w;
    }
    if (t < N_NODES) { A0[t*STRIDE + t] = 0.f; A1[t*STRIDE + t] = 0.f; }
    atomicAdd(&s_cntM, cM);
    atomicAdd(&s_cntN0, cN0);
    __syncthreads();

    // ---------------- D,W into registers (static-indexed, stays in VGPRs) --------------
    float Dreg[32], Wreg[32];
    #pragma unroll
    for (int k = 0; k < 32; ++k) {
        Dreg[k] = A0[i*STRIDE + jb + k];
        Wreg[k] = A1[i*STRIDE + jb + k];
    }

    // row sums of D^2 (rows == cols by symmetry)
    float rp = 0.f;
    #pragma unroll
    for (int k = 0; k < 32; ++k) rp = fmaf(Dreg[k], Dreg[k], rp);
    scrf[t] = rp;
    __syncthreads();
    if (t < N_NODES)
        r_s[t] = (scrf[t] + scrf[t + 128]) + (scrf[t + 256] + scrf[t + 384]);
    __syncthreads();

    // grand total of D^2 via per-wave butterfly (each wave holds full r_s)
    float mt = r_s[lane] + r_s[lane + 64];
    #pragma unroll
    for (int off = 32; off > 0; off >>= 1) mt += __shfl_xor(mt, off);

    const float Nmol  = (float)(1 + s_cntN0);
    const float Minv  = 1.0f / (float)(128 + s_cntM);
    const float invN  = 1.0f / Nmol;
    const float cmean = mt * invN * invN;

    // ---------------- Gram matrix Bg into registers ------------------------------------
    const float ri = r_s[i];
    float Bg[32];
    #pragma unroll
    for (int k = 0; k < 32; ++k) {
        int j = jb + k;
        float dv = Dreg[k];
        float v  = -0.5f * (dv*dv - ri*invN - r_s[j]*invN + cmean);
        bool msk = (dv > 0.f) || (i == j);
        Bg[k] = msk ? v : 0.f;
    }

    // ---------------- Power iteration: 3 ranks x 10 steps ------------------------------
    const float* ub = u_init  + (size_t)b * 384;
    const float* xb = x_noise + (size_t)b * 384;

    for (int kx = 0; kx < 3; ++kx) {
        if (t < N_NODES) u_s[t] = ub[t * 3 + kx];
        __syncthreads();

        for (int s = 0; s < 10; ++s) {
            float ulo = u_s[lane], uhi = u_s[lane + 64];
            float n2 = fmaf(ulo, ulo, uhi * uhi);
            #pragma unroll
            for (int off = 32; off > 0; off >>= 1) n2 += __shfl_xor(n2, off);
            float inv = 1.0f / fmaxf(sqrtf(n2), 0.001f);   // u/max(norm,1e-3), folded post-matvec

            float usel = (q < 2) ? ulo : uhi;              // wave-uniform half select
            float a0 = 0.f, a1 = 0.f;
            #pragma unroll
            for (int k = 0; k < 16; ++k) {
                a0 = fmaf(Bg[k],      rdlane(usel, lsel + k),      a0);
                a1 = fmaf(Bg[k + 16], rdlane(usel, lsel + k + 16), a1);
            }
            scrf[t] = a0 + a1;
            __syncthreads();
            if (t < N_NODES)
                u_s[t] = ((scrf[t] + scrf[t + 128]) + (scrf[t + 256] + scrf[t + 384])) * inv;
            __syncthreads();
        }

        // eig_sq of raw matvec output, scale, deflate Bg, accumulate X column
        float ulo = u_s[lane], uhi = u_s[lane + 64];
        float e2 = fmaf(ulo, ulo, uhi * uhi);
        #pragma unroll
        for (int off = 32; off > 0; off >>= 1) e2 += __shfl_xor(e2, off);
        float esc  = 1.0f / sqrtf(sqrtf(e2 + 0.01f));      // (eig_sq+0.01)^-0.25
        float ufi  = u_s[i] * esc;
        float uscl = ((q < 2) ? ulo : uhi) * esc;
        #pragma unroll
        for (int k = 0; k < 32; ++k)
            Bg[k] = fmaf(-ufi, rdlane(uscl, lsel + k), Bg[k]);   // A_lr -= u u^T

        if (t < N_NODES)
            ((float*)&Xs[t])[kx] = ufi + xb[t * 3 + kx];         // x0 = lowrank + noise
        __syncthreads();
    }

    // ---------------- Gradient descent: 10 steps ---------------------------------------
    // dx_i = (0.4/M) * sum_j W_ij (D_ij - DX_ij)/DX_ij * (x_i - x_j)
    const float stepc = 0.4f * Minv;
    for (int st = 0; st < 10; ++st) {
        float4 xi = Xs[i];
        float gx = 0.f, gy = 0.f, gz = 0.f;
        #pragma unroll
        for (int k = 0; k < 32; ++k) {
            float4 xj = Xs[jb + k];                         // wave-uniform broadcast
            float dx = xi.x - xj.x;
            float dy = xi.y - xj.y;
            float dz = xi.z - xj.z;
            float d2 = fmaf(dx, dx, fmaf(dy, dy, fmaf(dz, dz, 0.01f)));
            float DX = sqrtf(d2);
            float rv = __builtin_amdgcn_rcpf(DX);
            float c  = fmaf(Dreg[k] * rv, Wreg[k], -Wreg[k]);    // W*(D/DX - 1)
            gx = fmaf(c, dx, gx);
            gy = fmaf(c, dy, gy);
            gz = fmaf(c, dz, gz);
        }
        scr4[t] = make_float4(gx, gy, gz, 0.f);
        __syncthreads();
        if (t < N_NODES) {
            float4 p0 = scr4[t], p1 = scr4[t + 128], p2 = scr4[t + 256], p3 = scr4[t + 384];
            float sx = (p0.x + p1.x) + (p2.x + p3.x);
            float sy = (p0.y + p1.y) + (p2.y + p3.y);
            float sz = (p0.z + p1.z) + (p2.z + p3.z);
            float dxv = sx * stepc, dyv = sy * stepc, dzv = sz * stepc;
            float spd = sqrtf(fmaf(dxv, dxv, fmaf(dyv, dyv, fmaf(dzv, dzv, 0.001f))));
            float alpha = 0.1f + 4.9f * (float)(10 - st) * 0.1f;
            float scl = alpha * tanhf(spd / alpha) / spd;
            float4 xo = Xs[t];
            Xs[t] = make_float4(fmaf(dxv, scl, xo.x),
                                fmaf(dyv, scl, xo.y),
                                fmaf(dzv, scl, xo.z), 0.f);
        }
        __syncthreads();
    }

    // ---------------- Output: adj * distances(X), coalesced ----------------------------
    float* ob = out + (size_t)b * 16384;
    #pragma unroll 2
    for (int e = t; e < 16384; e += NTH) {
        int ii = e >> 7, jj = e & 127;
        float4 xi = Xs[ii], xj = Xs[jj];
        float dx = xi.x - xj.x, dy = xi.y - xj.y, dz = xi.z - xj.z;
        float d2 = fmaf(dx, dx, fmaf(dy, dy, fmaf(dz, dz, 0.01f)));
        float m  = (A0[ii*STRIDE + jj] > 0.f) ? 1.f : 0.f;   // adj mask recovered from D
        ob[e] = m * sqrtf(d2);
    }
}

extern "C" void kernel_launch(void* const* d_in, const int* in_sizes, int n_in,
                              void* d_out, int out_size, void* d_ws, size_t ws_size,
                              hipStream_t stream) {
    const float* edge_pred = (const float*)d_in[0];
    const int*   adj       = (const int*)  d_in[1];
    const float* dinit     = (const float*)d_in[2];
    const float* u_init    = (const float*)d_in[3];
    const float* x_noise   = (const float*)d_in[4];
    float*       out       = (float*)d_out;

    ts_gcn_kernel<<<512, NTH, 0, stream>>>(edge_pred, adj, dinit, u_init, x_noise, out);
}